// Round 5
// baseline (175.013 us; speedup 1.0000x reference)
//
#include <hip/hip_runtime.h>

#define T_DIM 512
#define B_DIM 8192
#define GBB 32          // batch columns per block -> full 128B cache lines
#define NCB 32          // time chunks (one per 32 threads)
#define LCB 16          // timesteps per chunk  (NCB*LCB == T_DIM)
#define NTH (GBB * NCB) // 1024 threads, 16 waves
#define GAMMA 0.99f

// Rounds 0-4 post-mortem: WRITE_SIZE is KB (no spill ever); four different
// register/occupancy structures all gave 50us @ 2TB/s -> limiter is the
// access pattern itself: (a) GB=16 read 64B half-lines, (b) burst-load/
// drain/compute with compiler sinking "clustered" loads (VGPR pinned 32-52).
// This version: global_load_lds staging (no VGPRs involved -> allocator
// can't defeat it) + counted-vmcnt software pipeline (T3/T4, m201-proven)
// + 32-column blocks (full 128B lines) + ratio-stash so pass B re-reads
// only v,rw (8B/elem, L3-resident).
//
// Wave-privacy: wave w's lanes are exactly threads w*64..w*64+63, and each
// slab element (c,bl) is consumed by thread c*32+bl, loaded by that same
// wave -> no barriers in either streaming loop; per-wave vmcnt discipline.
#define GLD(g, l) __builtin_amdgcn_global_load_lds(                          \
    (const __attribute__((address_space(1))) void*)(g),                      \
    (__attribute__((address_space(3))) void*)(l), 4, 0, 0)

__global__ __launch_bounds__(NTH)
void vtrace_main(const float* __restrict__ prob,
                 const float* __restrict__ aprob,
                 const float* __restrict__ v,
                 const float* __restrict__ nv,
                 const float* __restrict__ rw,
                 const int* __restrict__ act,
                 const int* __restrict__ dnn,
                 float* __restrict__ partials) {
    // 2 bufs x 8 arrays x 1024 elems: px,py,qx,qy,vv,rr,aa,dd   (64 KB)
    __shared__ unsigned int sl[2][8][NTH];
    __shared__ unsigned int st_r[LCB * NTH];   // ratio w/ done sign (64 KB)
    __shared__ float Sc[NTH];                  // per-chunk composite S (4 KB)
    __shared__ float Mc[NTH];                  // per-chunk composite M (4 KB)
    __shared__ float Cin[NTH];                 // carry entering chunk  (4 KB)
    __shared__ float red[32];

    const int tid = threadIdx.x;
    const int bl  = tid & (GBB - 1);
    const int c   = tid >> 5;
    const int wb  = tid & ~63;                 // wave-uniform LDS base index
    const int b   = blockIdx.x * GBB + bl;
    const size_t base = (size_t)(c * LCB) * B_DIM + b;

    const char* prob8  = (const char*)prob;
    const char* aprob8 = (const char*)aprob;
    const char* v4     = (const char*)v;
    const char* rw4    = (const char*)rw;
    const char* act4   = (const char*)act;
    const char* dnn4   = (const char*)dnn;

#define STAGE_A(i, k) do {                                                   \
        const size_t o = base + (size_t)(i) * B_DIM;                         \
        GLD(prob8  + o * 8,     &sl[k][0][wb]);                              \
        GLD(prob8  + o * 8 + 4, &sl[k][1][wb]);                              \
        GLD(aprob8 + o * 8,     &sl[k][2][wb]);                              \
        GLD(aprob8 + o * 8 + 4, &sl[k][3][wb]);                              \
        GLD(v4   + o * 4, &sl[k][4][wb]);                                    \
        GLD(rw4  + o * 4, &sl[k][5][wb]);                                    \
        GLD(act4 + o * 4, &sl[k][6][wb]);                                    \
        GLD(dnn4 + o * 4, &sl[k][7][wb]);                                    \
    } while (0)

#define STAGE_B(i, k) do {                                                   \
        const size_t o = base + (size_t)(i) * B_DIM;                         \
        GLD(v4  + o * 4, &sl[k][0][wb]);                                     \
        GLD(rw4 + o * 4, &sl[k][1][wb]);                                     \
    } while (0)

    // ---------------- pass A: stream slabs backward, 2-deep pipeline ------
    STAGE_A(LCB - 1, 0);
    STAGE_A(LCB - 2, 1);

    float S = 0.0f, M = 1.0f;
#pragma unroll
    for (int i = LCB - 1; i >= 0; --i) {
        const int k = (LCB - 1 - i) & 1;
        if (i > 0) asm volatile("s_waitcnt vmcnt(8)" ::: "memory");
        else       asm volatile("s_waitcnt vmcnt(0)" ::: "memory");

        const float pxv = __uint_as_float(sl[k][0][tid]);
        const float pyv = __uint_as_float(sl[k][1][tid]);
        const float qxv = __uint_as_float(sl[k][2][tid]);
        const float qyv = __uint_as_float(sl[k][3][tid]);
        const float vvv = __uint_as_float(sl[k][4][tid]);
        const float rrv = __uint_as_float(sl[k][5][tid]);
        const unsigned int aau = sl[k][6][tid];
        const unsigned int ddu = sl[k][7][tid];

        const float pa    = aau ? pyv : pxv;
        const float qa    = aau ? qyv : qxv;
        const float ratio = (pa * (qxv + qyv)) / ((pxv + pyv) * qa);
        const float rho   = fminf(ratio, 1.0f);
        const float m     = ddu ? 0.0f : GAMMA * rho;
        const float p     = rho * (rrv - vvv);

        st_r[i * NTH + tid] = __float_as_uint(ratio) | (ddu << 31);
        S = (vvv + p) + m * S;      // compose f_t(x) = s + m*x  (reverse)
        M = m * M;

        // LDS reads of buffer k retired before DMA reuses it
        asm volatile("s_waitcnt lgkmcnt(0)" ::: "memory");
        if (i >= 2) STAGE_A(i - 2, k);
    }

    Sc[tid] = S;
    Mc[tid] = M;

    // prefetch pass B's first two slabs; DMA flies during scan/barriers
    STAGE_B(LCB - 1, 0);
    STAGE_B(LCB - 2, 1);
    __syncthreads();

    // serial cross-chunk scan (reverse over time), one lane per column
    if (tid < GBB) {
        float carry = nv[(size_t)(T_DIM - 1) * B_DIM + blockIdx.x * GBB + tid];
#pragma unroll 8
        for (int cc = NCB - 1; cc >= 0; --cc) {
            Cin[cc * GBB + tid] = carry;       // carry entering chunk cc
            carry = fmaf(Mc[cc * GBB + tid], carry, Sc[cc * GBB + tid]);
        }
    }
    __syncthreads();

    // ---------------- pass B: re-stream v,rw; replay with true carry ------
    float carry  = Cin[tid];
    float critic = 0.0f, msum = 0.0f;
#pragma unroll
    for (int i = LCB - 1; i >= 0; --i) {
        const int k = (LCB - 1 - i) & 1;
        if (i > 0) asm volatile("s_waitcnt vmcnt(2)" ::: "memory");
        else       asm volatile("s_waitcnt vmcnt(0)" ::: "memory");

        const float vvv = __uint_as_float(sl[k][0][tid]);
        const float rrv = __uint_as_float(sl[k][1][tid]);
        const unsigned int u = st_r[i * NTH + tid];
        const float r_  = __uint_as_float(u & 0x7fffffffu);
        const float m   = ((int)u < 0) ? 0.0f : GAMMA * fminf(r_, 1.0f);
        const float p   = fminf(r_, 1.0f) * (rrv - vvv);   // same bits as A
        const float t_  = m * carry;
        const float adv = p + t_;                  // == -(v - vtrace)
        carry = (vvv + p) + t_;                    // vtrace_t
        critic = fmaf(adv, adv, critic);
        msum += (adv >= 0.0f) ? fminf(r_, 1.2f) * adv
                              : fmaxf(r_, 0.8f) * adv;

        asm volatile("s_waitcnt lgkmcnt(0)" ::: "memory");
        if (i >= 2) STAGE_B(i - 2, k);
    }

    // block reduction: wave64 shuffle then cross-wave via LDS (16 waves)
#pragma unroll
    for (int off = 32; off > 0; off >>= 1) {
        critic += __shfl_down(critic, off, 64);
        msum   += __shfl_down(msum, off, 64);
    }
    const int wave = tid >> 6;
    if ((tid & 63) == 0) { red[wave] = critic; red[16 + wave] = msum; }
    __syncthreads();
    if (tid == 0) {
        float cs = 0.0f, ms = 0.0f;
#pragma unroll
        for (int w = 0; w < 16; ++w) { cs += red[w]; ms += red[16 + w]; }
        partials[blockIdx.x]       = cs;   // critic partial
        partials[256 + blockIdx.x] = ms;   // min-surrogate partial
    }
#undef STAGE_A
#undef STAGE_B
}

__global__ void vtrace_final(const float* __restrict__ partials,
                             float* __restrict__ out) {
    __shared__ float red[8];
    const int tid = threadIdx.x;  // 256 threads, one per main-block partial
    float cs = partials[tid];
    float ms = partials[256 + tid];
#pragma unroll
    for (int off = 32; off > 0; off >>= 1) {
        cs += __shfl_down(cs, off, 64);
        ms += __shfl_down(ms, off, 64);
    }
    const int wave = tid >> 6;
    if ((tid & 63) == 0) { red[wave] = cs; red[4 + wave] = ms; }
    __syncthreads();
    if (tid == 0) {
        float c = 0.0f, m = 0.0f;
#pragma unroll
        for (int w = 0; w < 4; ++w) { c += red[w]; m += red[4 + w]; }
        const float invN = 1.0f / (float)((size_t)T_DIM * B_DIM); // exact pow2
        // total = actor + critic = -mean(min(surr)) + 0.5*mean(adv^2)
        out[0] = 0.5f * c * invN - m * invN;
    }
}

extern "C" void kernel_launch(void* const* d_in, const int* in_sizes, int n_in,
                              void* d_out, int out_size, void* d_ws, size_t ws_size,
                              hipStream_t stream) {
    const float* prob  = (const float*)d_in[0];
    const float* aprob = (const float*)d_in[1];
    const float* v     = (const float*)d_in[2];
    const float* nv    = (const float*)d_in[3];
    const float* rw    = (const float*)d_in[4];
    const int*   act   = (const int*)d_in[5];
    const int*   dnn   = (const int*)d_in[6];
    float* partials = (float*)d_ws;   // 512 floats used
    float* out      = (float*)d_out;

    vtrace_main<<<B_DIM / GBB, NTH, 0, stream>>>(prob, aprob, v, nv, rw,
                                                 act, dnn, partials);
    vtrace_final<<<1, 256, 0, stream>>>(partials, out);
}

// Round 8
// 174.561 us; speedup vs baseline: 1.0026x; 1.0026x over previous
//
#include <hip/hip_runtime.h>

#define T_DIM 512
#define B_DIM 8192
#define GBB 32          // batch columns per block
#define LANES 16        // lanes per row-group; each lane owns 2 adjacent cols
#define NCB 64          // time chunks  (tid>>4)
#define LCB 8           // timesteps per chunk (NCB*LCB == T_DIM)
#define NTH 1024        // 16 waves
#define GAMMA 0.99f

// Rounds 0-5: five structurally different kernels (registers, LDS staging,
// load clusters, DMA pipeline; VGPR 32-52; occ 33-66%) ALL land at
// 48-62us / ~2TB/s. Invariant was 4B/lane loads: 256B per
// wave-instruction -> ~2-3KB in flight per wave -> Little's-law cap at
// ~2TB/s under loaded-queue latency. This version widens transactions:
// each thread owns 2 adjacent columns, so prob/aprob are ONE float4
// (1KB/wave-instr) and v/rw/act/done are float2/int2 (512B/wave-instr);
// each 16-lane row-group touches a full 128B line. Cross-phase state
// (ratio+done packed) lives in LDS (spill-proof, r4-proven); phase B
// re-reads v,rw (block working set 128KB -> L2-hot).
// Rounds 6-7 failed in infra with this source; the only change here is
// dropping amdgpu_waves_per_eu(4,4) — the sole exotic construct, and not
// load-bearing (88KB LDS already pins 1 block/CU = 4 waves/EU).
__global__ __launch_bounds__(NTH)
void vtrace_main(const float* __restrict__ prob,
                 const float* __restrict__ aprob,
                 const float* __restrict__ v,
                 const float* __restrict__ nv,
                 const float* __restrict__ rw,
                 const int* __restrict__ act,
                 const int* __restrict__ dnn,
                 float* __restrict__ partials) {
    __shared__ unsigned int st_r[T_DIM * GBB];  // ratio w/ done sign (64 KB)
    __shared__ float Sc[NCB * GBB];             // chunk composite S   (8 KB)
    __shared__ float Mc[NCB * GBB];             // chunk composite M   (8 KB)
    __shared__ float Cin[NCB * GBB];            // carry entering chunk(8 KB)
    __shared__ float red[32];

    const int tid  = threadIdx.x;
    const int l    = tid & (LANES - 1);         // 0..15
    const int c    = tid >> 4;                  // 0..63
    const int col0 = 2 * l;                     // first of this thread's cols

    // element-pair index: (t*B_DIM + blockIdx*GBB + col0) / 2
    const size_t pbase = (size_t)blockIdx.x * (GBB / 2) + l;
    const size_t cbase = (size_t)(c * LCB) * (B_DIM / 2) + pbase;

    const float4* __restrict__ prob4  = (const float4*)prob;   // 2 cols x A=2
    const float4* __restrict__ aprob4 = (const float4*)aprob;
    const float2* __restrict__ v2     = (const float2*)v;
    const float2* __restrict__ rw2    = (const float2*)rw;
    const int2*   __restrict__ act2   = (const int2*)act;
    const int2*   __restrict__ dnn2   = (const int2*)dnn;

    // ---- phase A: stream chunk backward, full-width loads ---------------
    float S0 = 0.0f, M0 = 1.0f, S1 = 0.0f, M1 = 1.0f;
#pragma unroll
    for (int i = LCB - 1; i >= 0; --i) {
        const size_t o = cbase + (size_t)i * (B_DIM / 2);
        const float4 P = prob4[o];      // (p0x,p0y,p1x,p1y)
        const float4 Q = aprob4[o];
        const float2 V = v2[o];
        const float2 R = rw2[o];
        const int2   A = act2[o];
        const int2   D = dnn2[o];

        // column 0
        const float pa0 = A.x ? P.y : P.x;
        const float qa0 = A.x ? Q.y : Q.x;
        const float ra0 = (pa0 * (Q.x + Q.y)) / ((P.x + P.y) * qa0);
        const float rh0 = fminf(ra0, 1.0f);
        const float m0  = D.x ? 0.0f : GAMMA * rh0;
        const float p0  = rh0 * (R.x - V.x);
        // column 1
        const float pa1 = A.y ? P.w : P.z;
        const float qa1 = A.y ? Q.w : Q.z;
        const float ra1 = (pa1 * (Q.z + Q.w)) / ((P.z + P.w) * qa1);
        const float rh1 = fminf(ra1, 1.0f);
        const float m1  = D.y ? 0.0f : GAMMA * rh1;
        const float p1  = rh1 * (R.y - V.y);

        uint2 st;
        st.x = __float_as_uint(ra0) | ((unsigned)D.x << 31);
        st.y = __float_as_uint(ra1) | ((unsigned)D.y << 31);
        *(uint2*)&st_r[(c * LCB + i) * GBB + col0] = st;

        // compose f_t(x) = (v+p) + m*x in front of running composite
        S0 = (V.x + p0) + m0 * S0;  M0 = m0 * M0;
        S1 = (V.y + p1) + m1 * S1;  M1 = m1 * M1;
    }
    *(float2*)&Sc[c * GBB + col0] = make_float2(S0, S1);
    *(float2*)&Mc[c * GBB + col0] = make_float2(M0, M1);
    __syncthreads();

    // ---- serial cross-chunk scan (reverse), one lane per column ---------
    if (tid < GBB) {
        float carry = nv[(size_t)(T_DIM - 1) * B_DIM + blockIdx.x * GBB + tid];
#pragma unroll 8
        for (int cc = NCB - 1; cc >= 0; --cc) {
            Cin[cc * GBB + tid] = carry;       // carry entering chunk cc
            carry = fmaf(Mc[cc * GBB + tid], carry, Sc[cc * GBB + tid]);
        }
    }
    __syncthreads();

    // ---- phase B: replay chunk with true carry; v,rw re-read (L2-hot) ---
    const float2 cr = *(const float2*)&Cin[c * GBB + col0];
    float carry0 = cr.x, carry1 = cr.y;
    float critic = 0.0f, msum = 0.0f;
#pragma unroll
    for (int i = LCB - 1; i >= 0; --i) {
        const size_t o = cbase + (size_t)i * (B_DIM / 2);
        const float2 V = v2[o];
        const float2 R = rw2[o];
        const uint2  u = *(const uint2*)&st_r[(c * LCB + i) * GBB + col0];

        // column 0 (recompute p,s bit-identically to phase A)
        {
            const float r_  = __uint_as_float(u.x & 0x7fffffffu);
            const float m   = ((int)u.x < 0) ? 0.0f : GAMMA * fminf(r_, 1.0f);
            const float p   = fminf(r_, 1.0f) * (R.x - V.x);
            const float t_  = m * carry0;
            const float adv = p + t_;              // == -(v - vtrace)
            carry0 = (V.x + p) + t_;               // vtrace_t
            critic = fmaf(adv, adv, critic);
            msum += (adv >= 0.0f) ? fminf(r_, 1.2f) * adv
                                  : fmaxf(r_, 0.8f) * adv;
        }
        // column 1
        {
            const float r_  = __uint_as_float(u.y & 0x7fffffffu);
            const float m   = ((int)u.y < 0) ? 0.0f : GAMMA * fminf(r_, 1.0f);
            const float p   = fminf(r_, 1.0f) * (R.y - V.y);
            const float t_  = m * carry1;
            const float adv = p + t_;
            carry1 = (V.y + p) + t_;
            critic = fmaf(adv, adv, critic);
            msum += (adv >= 0.0f) ? fminf(r_, 1.2f) * adv
                                  : fmaxf(r_, 0.8f) * adv;
        }
    }

    // ---- block reduction: wave64 shuffle then cross-wave via LDS --------
#pragma unroll
    for (int off = 32; off > 0; off >>= 1) {
        critic += __shfl_down(critic, off, 64);
        msum   += __shfl_down(msum, off, 64);
    }
    const int wave = tid >> 6;
    if ((tid & 63) == 0) { red[wave] = critic; red[16 + wave] = msum; }
    __syncthreads();
    if (tid == 0) {
        float cs = 0.0f, ms = 0.0f;
#pragma unroll
        for (int w = 0; w < 16; ++w) { cs += red[w]; ms += red[16 + w]; }
        partials[blockIdx.x]       = cs;   // critic partial
        partials[256 + blockIdx.x] = ms;   // min-surrogate partial
    }
}

__global__ void vtrace_final(const float* __restrict__ partials,
                             float* __restrict__ out) {
    __shared__ float red[8];
    const int tid = threadIdx.x;  // 256 threads, one per main-block partial
    float cs = partials[tid];
    float ms = partials[256 + tid];
#pragma unroll
    for (int off = 32; off > 0; off >>= 1) {
        cs += __shfl_down(cs, off, 64);
        ms += __shfl_down(ms, off, 64);
    }
    const int wave = tid >> 6;
    if ((tid & 63) == 0) { red[wave] = cs; red[4 + wave] = ms; }
    __syncthreads();
    if (tid == 0) {
        float c = 0.0f, m = 0.0f;
#pragma unroll
        for (int w = 0; w < 4; ++w) { c += red[w]; m += red[4 + w]; }
        const float invN = 1.0f / (float)((size_t)T_DIM * B_DIM); // exact pow2
        // total = actor + critic = -mean(min(surr)) + 0.5*mean(adv^2)
        out[0] = 0.5f * c * invN - m * invN;
    }
}

extern "C" void kernel_launch(void* const* d_in, const int* in_sizes, int n_in,
                              void* d_out, int out_size, void* d_ws, size_t ws_size,
                              hipStream_t stream) {
    const float* prob  = (const float*)d_in[0];
    const float* aprob = (const float*)d_in[1];
    const float* v     = (const float*)d_in[2];
    const float* nv    = (const float*)d_in[3];
    const float* rw    = (const float*)d_in[4];
    const int*   act   = (const int*)d_in[5];
    const int*   dnn   = (const int*)d_in[6];
    float* partials = (float*)d_ws;   // 512 floats used
    float* out      = (float*)d_out;

    vtrace_main<<<B_DIM / GBB, NTH, 0, stream>>>(prob, aprob, v, nv, rw,
                                                 act, dnn, partials);
    vtrace_final<<<1, 256, 0, stream>>>(partials, out);
}